// Round 18
// baseline (1099.910 us; speedup 1.0000x reference)
//
#include <hip/hip_runtime.h>
#include <math.h>

#define N4    4096
#define FDIM  6
#define CC    1000
#define KP    1024
#define KP6   (6 * KP)
#define KNN   40
#define NRB   20
#define SSC   205

typedef __attribute__((ext_vector_type(8))) short bf16x8;
typedef __attribute__((ext_vector_type(4))) float f32x4;

__device__ __forceinline__ unsigned short f2bf(float f) {
    unsigned u = __float_as_uint(f);
    u = (u + 0x7fffu + ((u >> 16) & 1u)) >> 16;
    return (unsigned short)u;
}
__device__ __forceinline__ float bf2f(short s) {
    return __uint_as_float(((unsigned)(unsigned short)s) << 16);
}

// distance -> descending-sortable key (smaller d == larger key)
__device__ __forceinline__ unsigned d2key(float d) {
    unsigned u = __float_as_uint(d);
    return ((int)u < 0) ? u : (~u) ^ 0x80000000u;
}
__device__ __forceinline__ float key2d(unsigned k) {
    unsigned u = (k >> 31) ? k : (~k) ^ 0x80000000u;
    return __uint_as_float(u);
}

// ---------------- graph build ----------------

__global__ __launch_bounds__(256) void sqx_kernel(const float* __restrict__ x,
                                                  float* __restrict__ sq1,
                                                  float* __restrict__ xhat) {
    int n = blockIdx.x * blockDim.x + threadIdx.x;
    if (n >= N4) return;
    float s = 0.f;
#pragma unroll
    for (int f = 0; f < FDIM; ++f) {
        float v = x[n * FDIM + f];
        s += v * v;
        xhat[n * 18 + f] = v;
    }
    sq1[n] = s;
}

// ---------------- radix top-40 on distance keys (exact) ----------------

#define NHC 8
#define HSTRIDE 257

struct TopkSh {
    unsigned sv[N4];
    int hist[NHC * HSTRIDE];
    int sc[256];
    float red[512];
    unsigned short cidx[N4];
    unsigned s_pfx;
    int s_need, s_cnt, s_m;
};

__device__ __forceinline__ void hist_pick(TopkSh& sh, int level, int t, int lane, int w) {
    if (t < 256) {
        int cnt = 0;
#pragma unroll
        for (int c = 0; c < NHC; ++c) cnt += sh.hist[c * HSTRIDE + t];
        sh.sc[t] = cnt;
    }
    __syncthreads();
    if (w == 0) {
        int need = sh.s_need;
        unsigned pfx = sh.s_pfx;
        int c0 = sh.sc[4 * lane + 0], c1 = sh.sc[4 * lane + 1];
        int c2 = sh.sc[4 * lane + 2], c3 = sh.sc[4 * lane + 3];
        int s = c0 + c1 + c2 + c3;
        int suf = s;
#pragma unroll
        for (int off = 1; off < 64; off <<= 1) {
            int ov = __shfl_down(suf, off, 64);
            if (lane + off < 64) suf += ov;
        }
        int above = suf - s;
        int i3 = above + c3, i2 = i3 + c2, i1 = i2 + c1, i0 = i1 + c0;
        if (i3 >= need && i3 - c3 < need) { sh.s_need = need - (i3 - c3); sh.s_pfx = pfx | ((unsigned)(4 * lane + 3) << level); }
        if (i2 >= need && i2 - c2 < need) { sh.s_need = need - (i2 - c2); sh.s_pfx = pfx | ((unsigned)(4 * lane + 2) << level); }
        if (i1 >= need && i1 - c1 < need) { sh.s_need = need - (i1 - c1); sh.s_pfx = pfx | ((unsigned)(4 * lane + 1) << level); }
        if (i0 >= need && i0 - c0 < need) { sh.s_need = need - (i0 - c0); sh.s_pfx = pfx | ((unsigned)(4 * lane + 0) << level); }
    }
    __syncthreads();
}

__device__ void topk_select(TopkSh& sh, int n, int* __restrict__ idx,
                            float* __restrict__ val, float* __restrict__ rowsum) {
    int t = threadIdx.x, lane = t & 63, w = t >> 6;
    if (t == 0) { sh.s_pfx = 0u; sh.s_need = KNN; sh.s_cnt = 0; sh.s_m = 0; }
    for (int q = t; q < NHC * HSTRIDE; q += 512) sh.hist[q] = 0;
    __syncthreads();
    int* hw = &sh.hist[(t & 7) * HSTRIDE];

    // pass 1: full scan, top byte, run-length flushed
    {
        unsigned prevb = 0xFFFFFFFFu; int rl = 0;
        for (int i = t; i < N4; i += 512) {
            unsigned b = sh.sv[i] >> 24;
            if (b == prevb) ++rl;
            else { if (rl) atomicAdd(&hw[prevb], rl); prevb = b; rl = 1; }
        }
        if (rl) atomicAdd(&hw[prevb], rl);
    }
    __syncthreads();
    hist_pick(sh, 24, t, lane, w);
    unsigned b1 = sh.s_pfx >> 24;

    // compact ==b1 (ballot-aggregated), emit >b1 directly
    float psum = 0.f;
    for (int i = t; i < N4; i += 512) {
        unsigned u = sh.sv[i];
        unsigned tb = u >> 24;
        bool isc = (tb == b1);
        unsigned long long mm = __ballot(isc);
        int cw = __popcll(mm);
        int base = 0;
        if (lane == 0 && cw) base = atomicAdd(&sh.s_m, cw);
        base = __shfl(base, 0);
        if (isc) sh.cidx[base + __popcll(mm & ((1ull << lane) - 1ull))] = (unsigned short)i;

        bool isg = (tb > b1);
        unsigned long long mg = __ballot(isg);
        int gw = __popcll(mg);
        int gbase = 0;
        if (lane == 0 && gw) gbase = atomicAdd(&sh.s_cnt, gw);
        gbase = __shfl(gbase, 0);
        if (isg) {
            int p = gbase + __popcll(mg & ((1ull << lane) - 1ull));
            float v = __expf(-key2d(u));
            idx[(size_t)n * KNN + p] = i;
            val[(size_t)n * KNN + p] = v;
            psum += v;
        }
    }
    __syncthreads();
    int mcnt = sh.s_m;

    // levels 16, 8, 0 over the compacted list
    for (int level = 16; level >= 0; level -= 8) {
        for (int q = t; q < NHC * HSTRIDE; q += 512) sh.hist[q] = 0;
        __syncthreads();
        unsigned pfx = sh.s_pfx;
        for (int j = t; j < mcnt; j += 512) {
            unsigned u = sh.sv[sh.cidx[j]];
            if ((u >> (level + 8)) == (pfx >> (level + 8)))
                atomicAdd(&hw[(u >> level) & 255], 1);
        }
        __syncthreads();
        hist_pick(sh, level, t, lane, w);
    }
    unsigned Tbits = sh.s_pfx;
    float Tf = __expf(-key2d(Tbits));
    int needEq = sh.s_need;

    // collect >T within the compacted list
    for (int j = t; j < mcnt; j += 512) {
        unsigned u = sh.sv[sh.cidx[j]];
        if (u > Tbits) {
            int p = atomicAdd(&sh.s_cnt, 1);
            float v = __expf(-key2d(u));
            idx[(size_t)n * KNN + p] = (int)sh.cidx[j];
            val[(size_t)n * KNN + p] = v;
            psum += v;
        }
    }
    sh.red[t] = psum;
    __syncthreads();
    for (int o = 256; o; o >>= 1) { if (t < o) sh.red[t] += sh.red[t + o]; __syncthreads(); }
    if (t == 0) rowsum[n] = sh.red[0] + (float)needEq * Tf;

    // equals: earliest indices first (wave 0 ballot scan)
    if (t < 64) {
        int filled = KNN - needEq;
        for (int ib = 0; ib < N4 && filled < KNN; ib += 64) {
            bool eq = (sh.sv[ib + t] == Tbits);
            unsigned long long m = __ballot(eq);
            int pre = __popcll(m & ((1ull << t) - 1ull));
            if (eq && (filled + pre) < KNN) {
                idx[(size_t)n * KNN + filled + pre] = ib + t;
                val[(size_t)n * KNN + filled + pre] = Tf;
            }
            filled += __popcll(m);
        }
    }
}

__global__ __launch_bounds__(512) void topk_fused1(const float* __restrict__ x,
                                                   const float* __restrict__ sq1,
                                                   int* __restrict__ idx, float* __restrict__ val,
                                                   float* __restrict__ rowsum) {
    __shared__ TopkSh sh;
    __shared__ float xn[FDIM];
    __shared__ float sns;
    int n = blockIdx.x;
    int t = threadIdx.x;
    if (t < FDIM) xn[t] = x[n * FDIM + t];
    if (t == FDIM) sns = sq1[n];
    __syncthreads();
    float x0 = xn[0], x1 = xn[1], x2 = xn[2], x3 = xn[3], x4 = xn[4], x5 = xn[5];
    float sn = sns;
    for (int i = t; i < N4; i += 512) {
        const float2* xi = (const float2*)(x + i * FDIM);
        float2 p0 = xi[0], p1 = xi[1], p2 = xi[2];
        float d = x0 * p0.x + x1 * p0.y + x2 * p1.x + x3 * p1.y + x4 * p2.x + x5 * p2.y;
        float e = sn + sq1[i] - 2.f * d;
        sh.sv[i] = d2key(e);
    }
    topk_select(sh, n, idx, val, rowsum);
}

// graph-2: reads precomputed bf16 distance row
__global__ __launch_bounds__(512) void topk_radix(const unsigned short* __restrict__ S,
                                                  int* __restrict__ idx, float* __restrict__ val,
                                                  float* __restrict__ rowsum) {
    __shared__ TopkSh sh;
    int n = blockIdx.x;
    int t = threadIdx.x;
    const unsigned short* row = S + (size_t)n * N4;
    bf16x8 a = *(const bf16x8*)(row + 8 * t);
#pragma unroll
    for (int q = 0; q < 8; ++q) sh.sv[8 * t + q] = d2key(bf2f(a[q]));
    topk_select(sh, n, idx, val, rowsum);
}

// wnorm with inline rsqrt; rs = row sums (graph 1)
__global__ __launch_bounds__(256) void wnorm_kernel(float* __restrict__ wv,
                                                    const int* __restrict__ idx,
                                                    const float* __restrict__ rs) {
    int i = blockIdx.x * 256 + threadIdx.x;
    if (i >= N4 * KNN) return;
    int n = i / KNN;
    wv[i] = wv[i] * rsqrtf(rs[n]) * rsqrtf(rs[idx[i]]);
}

// graph-2 wnorm: also emits transposed [j][n] copies for the LDS recursion
__global__ __launch_bounds__(256) void wnorm_t_kernel(float* __restrict__ wv,
                                                      const int* __restrict__ idx,
                                                      const float* __restrict__ rs,
                                                      float* __restrict__ wvT,
                                                      int* __restrict__ idxT) {
    int i = blockIdx.x * 256 + threadIdx.x;
    if (i >= N4 * KNN) return;
    int n = i / KNN, j = i % KNN;
    int id = idx[i];
    float w = wv[i] * rsqrtf(rs[n]) * rsqrtf(rs[id]);
    wv[i] = w;
    wvT[(size_t)j * N4 + n] = w;
    idxT[(size_t)j * N4 + n] = id;
}

// Tn[n,:] = a*(Tc[n,:] - sum_j wv[n,j]*Tc[idx[n,j],:]) - b*Tp[n,:]   (F small, fp32)
__global__ __launch_bounds__(64) void spmv_cheb(const float* __restrict__ Tc,
                                                const float* __restrict__ Tp,
                                                float* __restrict__ Tn,
                                                const int* __restrict__ idx,
                                                const float* __restrict__ wv,
                                                int F, int sC, int sP, int sN,
                                                float a, float b) {
    __shared__ int   si[KNN];
    __shared__ float sw[KNN];
    int n = blockIdx.x;
    if (threadIdx.x < KNN) {
        si[threadIdx.x] = idx[(size_t)n * KNN + threadIdx.x];
        sw[threadIdx.x] = wv[(size_t)n * KNN + threadIdx.x];
    }
    __syncthreads();
    for (int c = threadIdx.x; c < F; c += blockDim.x) {
        float s = 0.f;
#pragma unroll 8
        for (int j = 0; j < KNN; ++j) s += sw[j] * Tc[(size_t)si[j] * sC + c];
        float v = a * (Tc[(size_t)n * sC + c] - s);
        if (b != 0.f) v -= b * Tp[(size_t)n * sP + c];
        Tn[(size_t)n * sN + c] = v;
    }
}

// LDS-resident Chebyshev recursion, column-sliced (8 cols per block).
// The recursion is column-separable: a block holds ALL 4096 rows of its
// 8-col slice in two ping-pong LDS buffers (2 x 64 KB dynamic LDS) and runs
// steps T1..T5 locally; the 40-neighbor gather is a local ds_read_b128.
// In-place on Tp is safe: Tp[r] is read only by the thread that overwrites
// it; gathers touch only the Tc buffer; barrier between steps.
// idxT/wvT are [j][n] so per-step coefficient reads are lane-coalesced.
// Pad col-groups (c0 >= 1000) propagate zeros (slice-0 pads are zero).
__global__ __launch_bounds__(256) void cheb_lds(const unsigned short* __restrict__ Tall0,
                                                unsigned short* __restrict__ TallW,
                                                const int* __restrict__ idxT,
                                                const float* __restrict__ wvT) {
    extern __shared__ unsigned short smem[];   // 2 * N4 * 8 shorts = 128 KB
    unsigned short* buf0 = smem;
    unsigned short* buf1 = smem + N4 * 8;
    int t = threadIdx.x;
    int c0 = blockIdx.x * 8;
    // load T0 slice (16 B per row, strided global reads; L2-shared across blocks)
    for (int s = 0; s < 16; ++s) {
        int r = t + 256 * s;
        *(bf16x8*)&buf0[r * 8] = *(const bf16x8*)(Tall0 + (size_t)r * KP6 + c0);
    }
    __syncthreads();
    unsigned short* Tc = buf0;
    unsigned short* Tp = buf1;
    float a = 1.f, b = 0.f;
    for (int k = 1; k <= 5; ++k) {
        for (int s = 0; s < 16; ++s) {
            int r = t + 256 * s;
            float acc[8] = {0.f, 0.f, 0.f, 0.f, 0.f, 0.f, 0.f, 0.f};
#pragma unroll 4
            for (int j = 0; j < KNN; ++j) {
                int ij = idxT[(size_t)j * N4 + r];     // coalesced across lanes
                float wj = wvT[(size_t)j * N4 + r];
                bf16x8 v = *(bf16x8*)&Tc[ij * 8];      // LDS gather
#pragma unroll
                for (int q = 0; q < 8; ++q) acc[q] += wj * bf2f(v[q]);
            }
            bf16x8 tc = *(bf16x8*)&Tc[r * 8];
            float o[8];
#pragma unroll
            for (int q = 0; q < 8; ++q) o[q] = a * (bf2f(tc[q]) - acc[q]);
            if (b != 0.f) {
                bf16x8 tp = *(bf16x8*)&Tp[r * 8];
#pragma unroll
                for (int q = 0; q < 8; ++q) o[q] -= b * bf2f(tp[q]);
            }
            bf16x8 ob;
#pragma unroll
            for (int q = 0; q < 8; ++q) ob[q] = (short)f2bf(o[q]);
            *(bf16x8*)&Tp[r * 8] = ob;                 // in-place (per-element safe)
            *(bf16x8*)(TallW + (size_t)r * KP6 + (size_t)k * KP + c0) = ob;
        }
        __syncthreads();
        unsigned short* tmp = Tc; Tc = Tp; Tp = tmp;
        a = 2.f; b = 1.f;
    }
}

// ---------------- bf16 conversion / transpose ----------------

__global__ __launch_bounds__(256) void cvt_bf16_kernel(const float* __restrict__ in,
                                                       unsigned short* __restrict__ out) {
    int i = blockIdx.x * 256 + threadIdx.x;
    int r = i >> 7, g = i & 127;
    bf16x8 v;
    if (g < 125) {
        float4 a = *(const float4*)(in + (size_t)r * CC + g * 8);
        float4 b = *(const float4*)(in + (size_t)r * CC + g * 8 + 4);
        v[0] = (short)f2bf(a.x); v[1] = (short)f2bf(a.y);
        v[2] = (short)f2bf(a.z); v[3] = (short)f2bf(a.w);
        v[4] = (short)f2bf(b.x); v[5] = (short)f2bf(b.y);
        v[6] = (short)f2bf(b.z); v[7] = (short)f2bf(b.w);
    } else {
#pragma unroll
        for (int q = 0; q < 8; ++q) v[q] = 0;
    }
    *(bf16x8*)(out + (size_t)r * KP6 + g * 8) = v;
}

// W2 [6*CC x CC] fp32 -> W2T6 [1024 rows(n)][KP6 cols(k)] bf16
__global__ __launch_bounds__(256) void w2t_kernel(const float* __restrict__ W2,
                                                  unsigned short* __restrict__ out) {
    __shared__ unsigned short tile[64][65];
    int t = threadIdx.x;
    int k0 = blockIdx.x * 64, n0 = blockIdx.y * 64, s = blockIdx.z;
#pragma unroll
    for (int p = 0; p < 16; ++p) {
        int i = p * 256 + t;
        int kk = i >> 6, nn = i & 63;
        int k = k0 + kk, n = n0 + nn;
        float v = (k < CC && n < CC) ? W2[((size_t)s * CC + k) * CC + n] : 0.f;
        tile[kk][nn] = f2bf(v);
    }
    __syncthreads();
#pragma unroll
    for (int p = 0; p < 16; ++p) {
        int i = p * 256 + t;
        int nn = i >> 6, kk = i & 63;
        out[(size_t)(n0 + nn) * KP6 + (size_t)s * KP + k0 + kk] = tile[kk][nn];
    }
}

// ---------------- MFMA GEMM cores ----------------

#define LDP 40
#define SP2 136                     // 128-tile epilogue staging pitch
#define SMEMN ((128 + 256) * LDP)   // 256-tile LDS
#define SP 264                      // 256-tile epilogue staging pitch

// 128x128-tile core
template<int STR>
__device__ __forceinline__ void gemm_core128(const unsigned short* __restrict__ Ag,
                                             const unsigned short* __restrict__ Bg,
                                             short* As, short* Bs, int t,
                                             int kbeg, int kend,
                                             f32x4 (&acc)[4][4]) {
    int l = t & 63, w = t >> 6;
    int wm = (w >> 1) * 64, wn = (w & 1) * 64;
    int ar0 = t >> 2, ak0 = (t & 3) * 8;
    int ar1 = (t + 256) >> 2, ak1 = ((t + 256) & 3) * 8;
    int lr = l & 15, lq8 = (l >> 4) * 8;
    for (int k0 = kbeg; k0 < kend; k0 += 32) {
        bf16x8 a0 = *(const bf16x8*)(Ag + (size_t)ar0 * STR + k0 + ak0);
        bf16x8 a1 = *(const bf16x8*)(Ag + (size_t)ar1 * STR + k0 + ak1);
        bf16x8 b0 = *(const bf16x8*)(Bg + (size_t)ar0 * STR + k0 + ak0);
        bf16x8 b1 = *(const bf16x8*)(Bg + (size_t)ar1 * STR + k0 + ak1);
        __syncthreads();
        *(bf16x8*)&As[ar0 * LDP + ak0] = a0;
        *(bf16x8*)&As[ar1 * LDP + ak1] = a1;
        *(bf16x8*)&Bs[ar0 * LDP + ak0] = b0;
        *(bf16x8*)&Bs[ar1 * LDP + ak1] = b1;
        __syncthreads();
        bf16x8 af[4], bfr[4];
#pragma unroll
        for (int mi = 0; mi < 4; ++mi)
            af[mi] = *(const bf16x8*)&As[(wm + mi * 16 + lr) * LDP + lq8];
#pragma unroll
        for (int ni = 0; ni < 4; ++ni)
            bfr[ni] = *(const bf16x8*)&Bs[(wn + ni * 16 + lr) * LDP + lq8];
#pragma unroll
        for (int mi = 0; mi < 4; ++mi)
#pragma unroll
            for (int ni = 0; ni < 4; ++ni)
                acc[mi][ni] = __builtin_amdgcn_mfma_f32_16x16x32_bf16(af[mi], bfr[ni], acc[mi][ni], 0, 0, 0);
    }
}

// 128x256-tile core
template<int STR>
__device__ __forceinline__ void gemm_core256(const unsigned short* __restrict__ Ag,
                                             const unsigned short* __restrict__ Bg,
                                             short* As, short* Bs, int t,
                                             int kbeg, int kend,
                                             f32x4 (&acc)[4][8]) {
    int l = t & 63, w = t >> 6;
    int wm = (w >> 1) * 64, wn = (w & 1) * 128;
    int ar = t >> 1, ak = (t & 1) * 16;
    int lr = l & 15, lq8 = (l >> 4) * 8;
    for (int k0 = kbeg; k0 < kend; k0 += 32) {
        bf16x8 a0 = *(const bf16x8*)(Ag + (size_t)ar * STR + k0 + ak);
        bf16x8 a1 = *(const bf16x8*)(Ag + (size_t)ar * STR + k0 + ak + 8);
        bf16x8 b0 = *(const bf16x8*)(Bg + (size_t)ar * STR + k0 + ak);
        bf16x8 b1 = *(const bf16x8*)(Bg + (size_t)ar * STR + k0 + ak + 8);
        bf16x8 b2 = *(const bf16x8*)(Bg + (size_t)(128 + ar) * STR + k0 + ak);
        bf16x8 b3 = *(const bf16x8*)(Bg + (size_t)(128 + ar) * STR + k0 + ak + 8);
        __syncthreads();
        *(bf16x8*)&As[ar * LDP + ak] = a0;
        *(bf16x8*)&As[ar * LDP + ak + 8] = a1;
        *(bf16x8*)&Bs[ar * LDP + ak] = b0;
        *(bf16x8*)&Bs[ar * LDP + ak + 8] = b1;
        *(bf16x8*)&Bs[(128 + ar) * LDP + ak] = b2;
        *(bf16x8*)&Bs[(128 + ar) * LDP + ak + 8] = b3;
        __syncthreads();
        bf16x8 af[4], bfr[8];
#pragma unroll
        for (int mi = 0; mi < 4; ++mi)
            af[mi] = *(const bf16x8*)&As[(wm + mi * 16 + lr) * LDP + lq8];
#pragma unroll
        for (int ni = 0; ni < 8; ++ni)
            bfr[ni] = *(const bf16x8*)&Bs[(wn + ni * 16 + lr) * LDP + lq8];
#pragma unroll
        for (int mi = 0; mi < 4; ++mi)
#pragma unroll
            for (int ni = 0; ni < 8; ++ni)
                acc[mi][ni] = __builtin_amdgcn_mfma_f32_16x16x32_bf16(af[mi], bfr[ni], acc[mi][ni], 0, 0, 0);
    }
}

// batched cheb2 GEMM: bf16 partials, 128x128 tiles, LDS-staged coalesced stores
// grid (32 m, 8 n, 6 z): same-A blocks 32 apart -> same XCD -> A L2 reuse
__global__ __launch_bounds__(256) void gemm_mfma_big(const unsigned short* __restrict__ A,
                                                     const unsigned short* __restrict__ B,
                                                     unsigned short* __restrict__ Cp) {
    __shared__ short smem[2 * 128 * LDP];
    short* As = smem;
    short* Bs = smem + 128 * LDP;
    int t = threadIdx.x;
    int m0 = blockIdx.x * 128, n0 = blockIdx.y * 128;
    int kz = blockIdx.z;
    unsigned short* C = Cp + (size_t)kz * N4 * CC;
    f32x4 acc[4][4] = {};
    gemm_core128<KP6>(A + (size_t)m0 * KP6, B + (size_t)n0 * KP6, As, Bs, t,
                      kz * KP, kz * KP + KP, acc);
    int l = t & 63, w = t >> 6;
    int wn = (w & 1) * 64;
    int lr = l & 15, lq4 = (l >> 4) * 4;
    int lrow = (w >> 1) * 16 + lq4;
#pragma unroll
    for (int mi = 0; mi < 4; ++mi) {
        __syncthreads();
#pragma unroll
        for (int ni = 0; ni < 4; ++ni) {
            int col = wn + ni * 16 + lr;
            f32x4 v = acc[mi][ni];
#pragma unroll
            for (int r = 0; r < 4; ++r) smem[(lrow + r) * SP2 + col] = (short)f2bf(v[r]);
        }
        __syncthreads();
#pragma unroll
        for (int q = 0; q < 2; ++q) {
            int row = q * 16 + (t >> 4);
            int col = (t & 15) * 8;
            int gm = m0 + (row >> 4) * 64 + mi * 16 + (row & 15);
            int gn = n0 + col;
            if (gn < CC) {
                bf16x8 vv = *(bf16x8*)&smem[row * SP2 + col];
                *(bf16x8*)(C + (size_t)gm * CC + gn) = vv;
            }
        }
    }
}

// out2 = relu(sum_z bf16 Cz + b2) -> fp32 out
__global__ __launch_bounds__(256) void bias_relu_merge(const unsigned short* __restrict__ Cp,
                                                       const float* __restrict__ b2,
                                                       float* __restrict__ out2) {
    size_t i8 = (size_t)blockIdx.x * 256 + threadIdx.x;
    if (i8 >= (size_t)N4 * CC / 8) return;
    size_t i = i8 * 8;
    int c = (int)(i % CC);
    const size_t S = (size_t)N4 * CC;
    float s[8] = {};
#pragma unroll
    for (int z = 0; z < 6; ++z) {
        bf16x8 v = *(const bf16x8*)(Cp + z * S + i);
#pragma unroll
        for (int q = 0; q < 8; ++q) s[q] += bf2f(v[q]);
    }
    float4 o0, o1;
    o0.x = fmaxf(s[0] + b2[c + 0], 0.f); o0.y = fmaxf(s[1] + b2[c + 1], 0.f);
    o0.z = fmaxf(s[2] + b2[c + 2], 0.f); o0.w = fmaxf(s[3] + b2[c + 3], 0.f);
    o1.x = fmaxf(s[4] + b2[c + 4], 0.f); o1.y = fmaxf(s[5] + b2[c + 5], 0.f);
    o1.z = fmaxf(s[6] + b2[c + 6], 0.f); o1.w = fmaxf(s[7] + b2[c + 7], 0.f);
    *(float4*)(out2 + i) = o0;
    *(float4*)(out2 + i + 4) = o1;
}

// gram over Tall slice 0 -> bf16 distances, 128x256 tiles, m-major XCD swizzle
__global__ __launch_bounds__(256, 2) void gram2_mfma(const unsigned short* __restrict__ Tall,
                                                     const float* __restrict__ sq2,
                                                     unsigned short* __restrict__ S) {
    __shared__ short smem[SMEMN];
    short* As = smem;
    short* Bs = smem + 128 * LDP;
    int t = threadIdx.x;
    int m0 = blockIdx.x * 128, n0 = blockIdx.y * 256;
    f32x4 acc[4][8] = {};
    gemm_core256<KP6>(Tall + (size_t)m0 * KP6, Tall + (size_t)n0 * KP6, As, Bs, t, 0, KP, acc);
    int l = t & 63, w = t >> 6;
    int wn = (w & 1) * 128;
    int lr = l & 15, lq4 = (l >> 4) * 4;
    int lrow = (w >> 1) * 16 + lq4;
#pragma unroll
    for (int mi = 0; mi < 4; ++mi) {
        __syncthreads();
        int mbase = m0 + (w >> 1) * 64 + mi * 16 + lq4;
#pragma unroll
        for (int ni = 0; ni < 8; ++ni) {
            int col = wn + ni * 16 + lr;
            float sn = sq2[n0 + col];
            f32x4 v = acc[mi][ni];
#pragma unroll
            for (int r = 0; r < 4; ++r)
                smem[(lrow + r) * SP + col] = (short)f2bf(sq2[mbase + r] + sn - 2.f * v[r]);
        }
        __syncthreads();
#pragma unroll
        for (int q = 0; q < 4; ++q) {
            int row = q * 8 + (t >> 5);
            int col = (t & 31) * 8;
            int gm = m0 + (row >> 4) * 64 + mi * 16 + (row & 15);
            int gn = n0 + col;
            bf16x8 vv = *(bf16x8*)&smem[row * SP + col];
            *(bf16x8*)(S + (size_t)gm * N4 + gn) = vv;
        }
    }
}

// ---------------- cheb conv 1 ----------------

__global__ __launch_bounds__(256) void cheb1_out_kernel(const float* __restrict__ xhat,
                                                        const float* __restrict__ W1,
                                                        const float* __restrict__ b1,
                                                        float* __restrict__ outF) {
    __shared__ float xh[16][18];
    int n0 = blockIdx.x * 16;
    int tid = threadIdx.x;
    for (int i = tid; i < 16 * 18; i += 256) xh[i / 18][i % 18] = xhat[(size_t)n0 * 18 + i];
    __syncthreads();
    for (int c0 = 0; c0 < CC; c0 += 256) {
        int c = c0 + tid;
        if (c < CC) {
            float acc[16];
#pragma unroll
            for (int r = 0; r < 16; ++r) acc[r] = 0.f;
            for (int f = 0; f < 18; ++f) {
                float wv = W1[(size_t)f * CC + c];
#pragma unroll
                for (int r = 0; r < 16; ++r) acc[r] += xh[r][f] * wv;
            }
            float bb = b1[c];
#pragma unroll
            for (int r = 0; r < 16; ++r)
                outF[(size_t)(n0 + r) * CC + c] = fmaxf(acc[r] + bb, 0.f);
        }
    }
}

// ---------------- regs (frobenius of O^T @ T) ----------------

__global__ __launch_bounds__(256) void matT6_partial(const float* __restrict__ O,
                                                     const float* __restrict__ T, int ts,
                                                     float* __restrict__ M) {
    __shared__ float sT[128][6];
    int t = threadIdx.x;
    int c = blockIdx.x * 256 + t;
    int n0 = blockIdx.y * 128;
    for (int i = t; i < 128 * 6; i += 256) {
        int nn = i / 6, f = i % 6;
        sT[nn][f] = T[(size_t)(n0 + nn) * ts + f];
    }
    __syncthreads();
    if (c >= CC) return;
    float a0 = 0, a1 = 0, a2 = 0, a3 = 0, a4 = 0, a5 = 0;
    for (int nn = 0; nn < 128; ++nn) {
        float o = O[(size_t)(n0 + nn) * CC + c];
        a0 += o * sT[nn][0]; a1 += o * sT[nn][1]; a2 += o * sT[nn][2];
        a3 += o * sT[nn][3]; a4 += o * sT[nn][4]; a5 += o * sT[nn][5];
    }
    atomicAdd(&M[0 * CC + c], a0);
    atomicAdd(&M[1 * CC + c], a1);
    atomicAdd(&M[2 * CC + c], a2);
    atomicAdd(&M[3 * CC + c], a3);
    atomicAdd(&M[4 * CC + c], a4);
    atomicAdd(&M[5 * CC + c], a5);
}

__global__ __launch_bounds__(256) void fro_kernel(const float* __restrict__ M, float* __restrict__ dst) {
    __shared__ float red[256];
    int t = threadIdx.x;
    int i = blockIdx.x * 256 + t;
    float v = (i < 6 * CC) ? M[i] : 0.f;
    red[t] = v * v;
    __syncthreads();
    for (int o = 128; o; o >>= 1) { if (t < o) red[t] += red[t + o]; __syncthreads(); }
    if (t == 0) atomicAdd(dst, red[0]);
}

// ---------------- pooling ----------------

__global__ __launch_bounds__(256) void vfr_kernel(const float* __restrict__ outF,
                                                  const int* __restrict__ sccs,
                                                  float* __restrict__ vfr) {
    int r = blockIdx.y;
    int c = blockIdx.x * 256 + threadIdx.x;
    if (c >= CC) return;
    int s0 = blockIdx.z * 41;
    float m = 0.f;
    for (int s = s0; s < s0 + 41; ++s) {
        int n = sccs[r * SSC + s];
        m = fmaxf(m, outF[(size_t)n * CC + c]);
    }
    atomicMax((int*)&vfr[(size_t)r * CC + c], __float_as_int(m));
}

__global__ __launch_bounds__(256) void sq2_kernel(const float* __restrict__ outF,
                                                  float* __restrict__ sq2) {
    int lane = threadIdx.x & 63, w = threadIdx.x >> 6;
    int n = blockIdx.x * 4 + w;
    const float* row = outF + (size_t)n * CC;
    float s = 0.f;
    for (int i = lane; i < CC; i += 64) { float v = row[i]; s += v * v; }
#pragma unroll
    for (int o = 32; o; o >>= 1) s += __shfl_down(s, o);
    if (lane == 0) sq2[n] = s;
}

// row-split column max; dst must be zeroed (values >= 0)
__global__ __launch_bounds__(256) void colmax_kernel(const float* __restrict__ O,
                                                     float* __restrict__ dst) {
    int c = blockIdx.x * 256 + threadIdx.x;
    if (c >= CC) return;
    int n0 = blockIdx.y * 64;
    float m = 0.f;
    for (int n = n0; n < n0 + 64; ++n) m = fmaxf(m, O[(size_t)n * CC + c]);
    atomicMax((int*)&dst[c], __float_as_int(m));
}

// ---------------- reeb branch ----------------

__global__ __launch_bounds__(256) void reeb_mm_kernel(const float* __restrict__ Lr,
                                                      const float* __restrict__ Vin,
                                                      const float* __restrict__ Vsub,
                                                      float* __restrict__ Vout, float a2) {
    int c = blockIdx.x * 256 + threadIdx.x;
    if (c >= CC) return;
    int r = blockIdx.y;
    float s = 0.f;
#pragma unroll
    for (int j = 0; j < NRB; ++j) s += Lr[r * NRB + j] * Vin[(size_t)j * CC + c];
    float v = a2 * s;
    if (Vsub) v -= Vsub[(size_t)r * CC + c];
    Vout[(size_t)r * CC + c] = v;
}

#define RKC 25
__global__ __launch_bounds__(256) void reeb_conv_splitk(const float* __restrict__ vfr,
                                                        const float* __restrict__ tr1,
                                                        const float* __restrict__ tr2,
                                                        const float* __restrict__ Wr,
                                                        float* __restrict__ rpre) {
    __shared__ float sA[NRB][RKC];
    int t = threadIdx.x;
    int kbase = blockIdx.y * RKC;
    for (int i = t; i < NRB * RKC; i += 256) {
        int r = i / RKC, kk = i % RKC;
        int kg = kbase + kk;
        float v;
        if (kg < CC)           v = vfr[(size_t)r * CC + kg];
        else if (kg < 2 * CC)  v = tr1[(size_t)r * CC + kg - CC];
        else                   v = tr2[(size_t)r * CC + kg - 2 * CC];
        sA[r][kk] = v;
    }
    __syncthreads();
    int c = blockIdx.x * 256 + t;
    if (c >= CC) return;
    float acc[NRB];
#pragma unroll
    for (int r = 0; r < NRB; ++r) acc[r] = 0.f;
    for (int kk = 0; kk < RKC; ++kk) {
        float wv = Wr[(size_t)(kbase + kk) * CC + c];
#pragma unroll
        for (int r = 0; r < NRB; ++r) acc[r] += sA[r][kk] * wv;
    }
#pragma unroll
    for (int r = 0; r < NRB; ++r) atomicAdd(&rpre[(size_t)r * CC + c], acc[r]);
}

__global__ __launch_bounds__(256) void reeb_max_kernel(const float* __restrict__ pre,
                                                       const float* __restrict__ br,
                                                       float* __restrict__ rbm) {
    int c = blockIdx.x * 256 + threadIdx.x;
    if (c >= CC) return;
    float bb = br[c];
    float m = 0.f;
    for (int r = 0; r < NRB; ++r) m = fmaxf(m, fmaxf(pre[(size_t)r * CC + c] + bb, 0.f));
    rbm[c] = m;
}

// ---------------- FC head ----------------

__global__ __launch_bounds__(256) void fc1_kernel(const float* __restrict__ rbm,
                                                  const float* __restrict__ otm,
                                                  const float* __restrict__ w,
                                                  float* __restrict__ h1pre) {
    int j = blockIdx.x * 256 + threadIdx.x;
    if (j >= 512) return;
    int i0 = blockIdx.y * 250;
    float s = 0.f;
    for (int i = i0; i < i0 + 250; ++i) {
        float v = (i < CC) ? rbm[i] : otm[i - CC];
        s += v * w[(size_t)i * 512 + j];
    }
    atomicAdd(&h1pre[j], s);
}

__global__ __launch_bounds__(512) void fc23_kernel(const float* __restrict__ h1pre,
                                                   const float* __restrict__ b1f,
                                                   const float* __restrict__ w2,
                                                   const float* __restrict__ b2f,
                                                   const float* __restrict__ w3,
                                                   const float* __restrict__ b3f,
                                                   float* __restrict__ dout) {
    __shared__ float h1[512];
    __shared__ float h2[128];
    int t = threadIdx.x;
    h1[t] = fmaxf(h1pre[t] + b1f[t], 0.f);
    __syncthreads();
    if (t < 128) {
        float s = b2f[t];
        for (int i = 0; i < 512; ++i) s += h1[i] * w2[(size_t)i * 128 + t];
        h2[t] = fmaxf(s, 0.f);
    }
    __syncthreads();
    if (t < 40) {
        float s = b3f[t];
        for (int i = 0; i < 128; ++i) s += h2[i] * w3[(size_t)i * 40 + t];
        dout[t] = s;
    }
}

__global__ __launch_bounds__(256) void finalize_kernel(const float* __restrict__ racc,
                                                       const float* __restrict__ f1w,
                                                       const float* __restrict__ f1b,
                                                       const float* __restrict__ f2w,
                                                       const float* __restrict__ f2b,
                                                       const float* __restrict__ f3w,
                                                       const float* __restrict__ f3b,
                                                       float* __restrict__ dout) {
    __shared__ float red[256];
    __shared__ float res[3];
    int t = threadIdx.x;
    float s1 = 0.f, s2 = 0.f, s3 = 0.f;
    for (int i = t; i < 2000; i += 256) { float v = f1w[(size_t)i * 512]; s1 += v * v; }
    for (int i = t; i < 512; i += 256) { float v = f2w[(size_t)i * 128]; s2 += v * v; }
    if (t < 128) { float v = f3w[(size_t)t * 40]; s3 = v * v; }

    red[t] = s1; __syncthreads();
    for (int o = 128; o; o >>= 1) { if (t < o) red[t] += red[t + o]; __syncthreads(); }
    if (t == 0) res[0] = red[0];
    __syncthreads();
    red[t] = s2; __syncthreads();
    for (int o = 128; o; o >>= 1) { if (t < o) red[t] += red[t + o]; __syncthreads(); }
    if (t == 0) res[1] = red[0];
    __syncthreads();
    red[t] = s3; __syncthreads();
    for (int o = 128; o; o >>= 1) { if (t < o) red[t] += red[t + o]; __syncthreads(); }
    if (t == 0) res[2] = red[0];
    __syncthreads();

    if (t == 0) {
        dout[40] = sqrtf(racc[0]);
        dout[41] = sqrtf(racc[1]);
        dout[42] = res[0];
        dout[43] = f1b[0] * f1b[0];
        dout[44] = res[1];
        dout[45] = f2b[0] * f2b[0];
        dout[46] = res[2];
        dout[47] = f3b[0] * f3b[0];
    }
}

// ---------------- host ----------------

extern "C" void kernel_launch(void* const* d_in, const int* in_sizes, int n_in,
                              void* d_out, int out_size, void* d_ws, size_t ws_size,
                              hipStream_t stream) {
    const float* x    = (const float*)d_in[0];
    const float* Lr   = (const float*)d_in[5];
    const int*   sccs = (const int*)d_in[6];
    const float* W1   = (const float*)d_in[7];
    const float* b1   = (const float*)d_in[8];
    const float* W2   = (const float*)d_in[9];
    const float* b2   = (const float*)d_in[10];
    const float* Wr   = (const float*)d_in[11];
    const float* br   = (const float*)d_in[12];
    const float* f1w  = (const float*)d_in[13];
    const float* f1b  = (const float*)d_in[14];
    const float* f2w  = (const float*)d_in[15];
    const float* f2b  = (const float*)d_in[16];
    const float* f3w  = (const float*)d_in[17];
    const float* f3b  = (const float*)d_in[18];
    float* dout = (float*)d_out;

    char* ws = (char*)d_ws;
    size_t off = 0;
    auto alloc = [&](size_t bytes) -> char* {
        char* p = ws + off;
        off = (off + bytes + 255) & ~(size_t)255;
        return p;
    };
    float* outF = (float*)alloc((size_t)N4 * CC * 4);             // graph1 out, then reused as out2
    unsigned short* Cpb = (unsigned short*)alloc((size_t)6 * N4 * CC * 2);  // bf16 split-K partials
    unsigned short* Sb  = (unsigned short*)alloc((size_t)N4 * N4 * 2);      // bf16 distances
    unsigned short* Tall = (unsigned short*)alloc((size_t)N4 * KP6 * 2);
    unsigned short* W2T6 = Sb;   // alias: Sb dead after topk2
    float* xhat = (float*)alloc((size_t)N4 * 18 * 4);
    float* sq1  = (float*)alloc(N4 * 4);
    float* sq2  = (float*)alloc(N4 * 4);
    float* rs1  = (float*)alloc(N4 * 4);
    float* rs2  = (float*)alloc(N4 * 4);
    float* wv1  = (float*)alloc((size_t)N4 * KNN * 4);
    float* wv2  = (float*)alloc((size_t)N4 * KNN * 4);
    int*   ix1  = (int*)alloc((size_t)N4 * KNN * 4);
    int*   ix2  = (int*)alloc((size_t)N4 * KNN * 4);
    float* wvT  = (float*)alloc((size_t)N4 * KNN * 4);
    int*   ixT  = (int*)alloc((size_t)N4 * KNN * 4);
    float* t2x  = (float*)alloc((size_t)N4 * FDIM * 4);
    float* tr1  = (float*)alloc((size_t)NRB * CC * 4);
    float* tr2  = (float*)alloc((size_t)NRB * CC * 4);
    char*  zbase = ws + off;
    float* Mb   = (float*)alloc(6 * CC * 4);
    float* Mb2  = (float*)alloc(6 * CC * 4);
    float* rbm  = (float*)alloc(CC * 4);
    float* otm  = (float*)alloc(CC * 4);
    float* h1p  = (float*)alloc(512 * 4);
    float* racc = (float*)alloc(64 * 4);
    float* rpre = (float*)alloc((size_t)NRB * CC * 4);
    float* vfr  = (float*)alloc((size_t)NRB * CC * 4);
    size_t zlen = (size_t)((ws + off) - zbase);
    if (off > ws_size) return;

    hipMemsetAsync(zbase, 0, zlen, stream);

    // ---- graph 1 (on x): fused distance + top-40 ----
    sqx_kernel<<<(N4 + 255) / 256, 256, 0, stream>>>(x, sq1, xhat);
    topk_fused1<<<N4, 512, 0, stream>>>(x, sq1, ix1, wv1, rs1);
    wnorm_kernel<<<(N4 * KNN + 255) / 256, 256, 0, stream>>>(wv1, ix1, rs1);

    // ---- cheb conv 1 ----
    spmv_cheb<<<N4, 64, 0, stream>>>(xhat, xhat, xhat + 6, ix1, wv1, FDIM, 18, 18, 18, 1.f, 0.f);
    spmv_cheb<<<N4, 64, 0, stream>>>(xhat + 6, xhat, xhat + 12, ix1, wv1, FDIM, 18, 18, 18, 2.f, 1.f);
    cheb1_out_kernel<<<N4 / 16, 256, 0, stream>>>(xhat, W1, b1, outF);

    matT6_partial<<<dim3(4, 32), 256, 0, stream>>>(outF, xhat + 6, 18, Mb);
    fro_kernel<<<24, 256, 0, stream>>>(Mb, racc + 0);

    vfr_kernel<<<dim3(4, NRB, 5), 256, 0, stream>>>(outF, sccs, vfr);

    // ---- graph 2 (on outF) ----
    sq2_kernel<<<N4 / 4, 256, 0, stream>>>(outF, sq2);
    cvt_bf16_kernel<<<N4 * 128 / 256, 256, 0, stream>>>(outF, Tall);  // slice 0
    gram2_mfma<<<dim3(N4 / 128, N4 / 256), 256, 0, stream>>>(Tall, sq2, Sb);
    topk_radix<<<N4, 512, 0, stream>>>(Sb, ix2, wv2, rs2);
    wnorm_t_kernel<<<(N4 * KNN + 255) / 256, 256, 0, stream>>>(wv2, ix2, rs2, wvT, ixT);

    // Sb dead -> build W2T6 in its space
    w2t_kernel<<<dim3(16, 16, 6), 256, 0, stream>>>(W2, W2T6);

    spmv_cheb<<<N4, 64, 0, stream>>>(x, x, t2x, ix2, wv2, FDIM, FDIM, FDIM, FDIM, 1.f, 0.f);

    // ---- LDS-resident Chebyshev recursion: all 5 steps in one kernel ----
    cheb_lds<<<128, 256, 2 * N4 * 8 * sizeof(unsigned short), stream>>>(Tall, Tall, ixT, wvT);

    // ---- batched K=6144 GEMM (split-K=6, bf16 partials, 128-tiles, XCD-swizzled) ----
    gemm_mfma_big<<<dim3(N4 / 128, 8, 6), 256, 0, stream>>>(Tall, W2T6, Cpb);
    bias_relu_merge<<<(int)(((size_t)N4 * CC / 8 + 255) / 256), 256, 0, stream>>>(Cpb, b2, outF);

    matT6_partial<<<dim3(4, 32), 256, 0, stream>>>(outF, t2x, FDIM, Mb2);
    fro_kernel<<<24, 256, 0, stream>>>(Mb2, racc + 1);

    colmax_kernel<<<dim3(4, 64), 256, 0, stream>>>(outF, otm);

    // ---- reeb cheb conv (K=3) ----
    reeb_mm_kernel<<<dim3(4, NRB), 256, 0, stream>>>(Lr, vfr, nullptr, tr1, 1.f);
    reeb_mm_kernel<<<dim3(4, NRB), 256, 0, stream>>>(Lr, tr1, vfr, tr2, 2.f);
    reeb_conv_splitk<<<dim3(4, 120), 256, 0, stream>>>(vfr, tr1, tr2, Wr, rpre);
    reeb_max_kernel<<<4, 256, 0, stream>>>(rpre, br, rbm);

    // ---- FC head ----
    fc1_kernel<<<dim3(2, 8), 256, 0, stream>>>(rbm, otm, f1w, h1p);
    fc23_kernel<<<1, 512, 0, stream>>>(h1p, f1b, f2w, f2b, f3w, f3b, dout);
    finalize_kernel<<<1, 256, 0, stream>>>(racc, f1w, f1b, f2w, f2b, f3w, f3b, dout);
}

// Round 19
// 713.879 us; speedup vs baseline: 1.5408x; 1.5408x over previous
//
#include <hip/hip_runtime.h>
#include <math.h>

#define N4    4096
#define FDIM  6
#define CC    1000
#define KP    1024
#define KP6   (6 * KP)
#define KNN   40
#define NRB   20
#define SSC   205

typedef __attribute__((ext_vector_type(8))) short bf16x8;
typedef __attribute__((ext_vector_type(4))) float f32x4;

__device__ __forceinline__ unsigned short f2bf(float f) {
    unsigned u = __float_as_uint(f);
    u = (u + 0x7fffu + ((u >> 16) & 1u)) >> 16;
    return (unsigned short)u;
}
__device__ __forceinline__ float bf2f(short s) {
    return __uint_as_float(((unsigned)(unsigned short)s) << 16);
}

// distance -> descending-sortable key (smaller d == larger key)
__device__ __forceinline__ unsigned d2key(float d) {
    unsigned u = __float_as_uint(d);
    return ((int)u < 0) ? u : (~u) ^ 0x80000000u;
}
__device__ __forceinline__ float key2d(unsigned k) {
    unsigned u = (k >> 31) ? k : (~k) ^ 0x80000000u;
    return __uint_as_float(u);
}

// ---------------- graph build ----------------

__global__ __launch_bounds__(256) void sqx_kernel(const float* __restrict__ x,
                                                  float* __restrict__ sq1,
                                                  float* __restrict__ xhat) {
    int n = blockIdx.x * blockDim.x + threadIdx.x;
    if (n >= N4) return;
    float s = 0.f;
#pragma unroll
    for (int f = 0; f < FDIM; ++f) {
        float v = x[n * FDIM + f];
        s += v * v;
        xhat[n * 18 + f] = v;
    }
    sq1[n] = s;
}

// ---------------- radix top-40 on distance keys (exact) ----------------

#define NHC 8
#define HSTRIDE 257

struct TopkSh {
    unsigned sv[N4];
    int hist[NHC * HSTRIDE];
    int sc[256];
    float red[512];
    unsigned short cidx[N4];
    unsigned s_pfx;
    int s_need, s_cnt, s_m;
};

__device__ __forceinline__ void hist_pick(TopkSh& sh, int level, int t, int lane, int w) {
    if (t < 256) {
        int cnt = 0;
#pragma unroll
        for (int c = 0; c < NHC; ++c) cnt += sh.hist[c * HSTRIDE + t];
        sh.sc[t] = cnt;
    }
    __syncthreads();
    if (w == 0) {
        int need = sh.s_need;
        unsigned pfx = sh.s_pfx;
        int c0 = sh.sc[4 * lane + 0], c1 = sh.sc[4 * lane + 1];
        int c2 = sh.sc[4 * lane + 2], c3 = sh.sc[4 * lane + 3];
        int s = c0 + c1 + c2 + c3;
        int suf = s;
#pragma unroll
        for (int off = 1; off < 64; off <<= 1) {
            int ov = __shfl_down(suf, off, 64);
            if (lane + off < 64) suf += ov;
        }
        int above = suf - s;
        int i3 = above + c3, i2 = i3 + c2, i1 = i2 + c1, i0 = i1 + c0;
        if (i3 >= need && i3 - c3 < need) { sh.s_need = need - (i3 - c3); sh.s_pfx = pfx | ((unsigned)(4 * lane + 3) << level); }
        if (i2 >= need && i2 - c2 < need) { sh.s_need = need - (i2 - c2); sh.s_pfx = pfx | ((unsigned)(4 * lane + 2) << level); }
        if (i1 >= need && i1 - c1 < need) { sh.s_need = need - (i1 - c1); sh.s_pfx = pfx | ((unsigned)(4 * lane + 1) << level); }
        if (i0 >= need && i0 - c0 < need) { sh.s_need = need - (i0 - c0); sh.s_pfx = pfx | ((unsigned)(4 * lane + 0) << level); }
    }
    __syncthreads();
}

__device__ void topk_select(TopkSh& sh, int n, int* __restrict__ idx,
                            float* __restrict__ val, float* __restrict__ rowsum) {
    int t = threadIdx.x, lane = t & 63, w = t >> 6;
    if (t == 0) { sh.s_pfx = 0u; sh.s_need = KNN; sh.s_cnt = 0; sh.s_m = 0; }
    for (int q = t; q < NHC * HSTRIDE; q += 512) sh.hist[q] = 0;
    __syncthreads();
    int* hw = &sh.hist[(t & 7) * HSTRIDE];

    // pass 1: full scan, top byte, run-length flushed
    {
        unsigned prevb = 0xFFFFFFFFu; int rl = 0;
        for (int i = t; i < N4; i += 512) {
            unsigned b = sh.sv[i] >> 24;
            if (b == prevb) ++rl;
            else { if (rl) atomicAdd(&hw[prevb], rl); prevb = b; rl = 1; }
        }
        if (rl) atomicAdd(&hw[prevb], rl);
    }
    __syncthreads();
    hist_pick(sh, 24, t, lane, w);
    unsigned b1 = sh.s_pfx >> 24;

    // compact ==b1 (ballot-aggregated), emit >b1 directly
    float psum = 0.f;
    for (int i = t; i < N4; i += 512) {
        unsigned u = sh.sv[i];
        unsigned tb = u >> 24;
        bool isc = (tb == b1);
        unsigned long long mm = __ballot(isc);
        int cw = __popcll(mm);
        int base = 0;
        if (lane == 0 && cw) base = atomicAdd(&sh.s_m, cw);
        base = __shfl(base, 0);
        if (isc) sh.cidx[base + __popcll(mm & ((1ull << lane) - 1ull))] = (unsigned short)i;

        bool isg = (tb > b1);
        unsigned long long mg = __ballot(isg);
        int gw = __popcll(mg);
        int gbase = 0;
        if (lane == 0 && gw) gbase = atomicAdd(&sh.s_cnt, gw);
        gbase = __shfl(gbase, 0);
        if (isg) {
            int p = gbase + __popcll(mg & ((1ull << lane) - 1ull));
            float v = __expf(-key2d(u));
            idx[(size_t)n * KNN + p] = i;
            val[(size_t)n * KNN + p] = v;
            psum += v;
        }
    }
    __syncthreads();
    int mcnt = sh.s_m;

    // levels 16, 8, 0 over the compacted list
    for (int level = 16; level >= 0; level -= 8) {
        for (int q = t; q < NHC * HSTRIDE; q += 512) sh.hist[q] = 0;
        __syncthreads();
        unsigned pfx = sh.s_pfx;
        for (int j = t; j < mcnt; j += 512) {
            unsigned u = sh.sv[sh.cidx[j]];
            if ((u >> (level + 8)) == (pfx >> (level + 8)))
                atomicAdd(&hw[(u >> level) & 255], 1);
        }
        __syncthreads();
        hist_pick(sh, level, t, lane, w);
    }
    unsigned Tbits = sh.s_pfx;
    float Tf = __expf(-key2d(Tbits));
    int needEq = sh.s_need;

    // collect >T within the compacted list
    for (int j = t; j < mcnt; j += 512) {
        unsigned u = sh.sv[sh.cidx[j]];
        if (u > Tbits) {
            int p = atomicAdd(&sh.s_cnt, 1);
            float v = __expf(-key2d(u));
            idx[(size_t)n * KNN + p] = (int)sh.cidx[j];
            val[(size_t)n * KNN + p] = v;
            psum += v;
        }
    }
    sh.red[t] = psum;
    __syncthreads();
    for (int o = 256; o; o >>= 1) { if (t < o) sh.red[t] += sh.red[t + o]; __syncthreads(); }
    if (t == 0) rowsum[n] = sh.red[0] + (float)needEq * Tf;

    // equals: earliest indices first (wave 0 ballot scan)
    if (t < 64) {
        int filled = KNN - needEq;
        for (int ib = 0; ib < N4 && filled < KNN; ib += 64) {
            bool eq = (sh.sv[ib + t] == Tbits);
            unsigned long long m = __ballot(eq);
            int pre = __popcll(m & ((1ull << t) - 1ull));
            if (eq && (filled + pre) < KNN) {
                idx[(size_t)n * KNN + filled + pre] = ib + t;
                val[(size_t)n * KNN + filled + pre] = Tf;
            }
            filled += __popcll(m);
        }
    }
}

__global__ __launch_bounds__(512) void topk_fused1(const float* __restrict__ x,
                                                   const float* __restrict__ sq1,
                                                   int* __restrict__ idx, float* __restrict__ val,
                                                   float* __restrict__ rowsum) {
    __shared__ TopkSh sh;
    __shared__ float xn[FDIM];
    __shared__ float sns;
    int n = blockIdx.x;
    int t = threadIdx.x;
    if (t < FDIM) xn[t] = x[n * FDIM + t];
    if (t == FDIM) sns = sq1[n];
    __syncthreads();
    float x0 = xn[0], x1 = xn[1], x2 = xn[2], x3 = xn[3], x4 = xn[4], x5 = xn[5];
    float sn = sns;
    for (int i = t; i < N4; i += 512) {
        const float2* xi = (const float2*)(x + i * FDIM);
        float2 p0 = xi[0], p1 = xi[1], p2 = xi[2];
        float d = x0 * p0.x + x1 * p0.y + x2 * p1.x + x3 * p1.y + x4 * p2.x + x5 * p2.y;
        float e = sn + sq1[i] - 2.f * d;
        sh.sv[i] = d2key(e);
    }
    topk_select(sh, n, idx, val, rowsum);
}

// graph-2: reads precomputed bf16 distance row
__global__ __launch_bounds__(512) void topk_radix(const unsigned short* __restrict__ S,
                                                  int* __restrict__ idx, float* __restrict__ val,
                                                  float* __restrict__ rowsum) {
    __shared__ TopkSh sh;
    int n = blockIdx.x;
    int t = threadIdx.x;
    const unsigned short* row = S + (size_t)n * N4;
    bf16x8 a = *(const bf16x8*)(row + 8 * t);
#pragma unroll
    for (int q = 0; q < 8; ++q) sh.sv[8 * t + q] = d2key(bf2f(a[q]));
    topk_select(sh, n, idx, val, rowsum);
}

// wnorm with inline rsqrt; rs = row sums
__global__ __launch_bounds__(256) void wnorm_kernel(float* __restrict__ wv,
                                                    const int* __restrict__ idx,
                                                    const float* __restrict__ rs) {
    int i = blockIdx.x * 256 + threadIdx.x;
    if (i >= N4 * KNN) return;
    int n = i / KNN;
    wv[i] = wv[i] * rsqrtf(rs[n]) * rsqrtf(rs[idx[i]]);
}

// Tn[n,:] = a*(Tc[n,:] - sum_j wv[n,j]*Tc[idx[n,j],:]) - b*Tp[n,:]   (F small, fp32)
__global__ __launch_bounds__(64) void spmv_cheb(const float* __restrict__ Tc,
                                                const float* __restrict__ Tp,
                                                float* __restrict__ Tn,
                                                const int* __restrict__ idx,
                                                const float* __restrict__ wv,
                                                int F, int sC, int sP, int sN,
                                                float a, float b) {
    __shared__ int   si[KNN];
    __shared__ float sw[KNN];
    int n = blockIdx.x;
    if (threadIdx.x < KNN) {
        si[threadIdx.x] = idx[(size_t)n * KNN + threadIdx.x];
        sw[threadIdx.x] = wv[(size_t)n * KNN + threadIdx.x];
    }
    __syncthreads();
    for (int c = threadIdx.x; c < F; c += blockDim.x) {
        float s = 0.f;
#pragma unroll 8
        for (int j = 0; j < KNN; ++j) s += sw[j] * Tc[(size_t)si[j] * sC + c];
        float v = a * (Tc[(size_t)n * sC + c] - s);
        if (b != 0.f) v -= b * Tp[(size_t)n * sP + c];
        Tn[(size_t)n * sN + c] = v;
    }
}

// bf16-resident recursion over Tall slices (row stride KP6)
__global__ __launch_bounds__(256) void spmv_cheb_bf(const unsigned short* __restrict__ Tcbf,
                                                    const unsigned short* __restrict__ Tpbf,
                                                    unsigned short* __restrict__ Tnbf,
                                                    const int* __restrict__ idx,
                                                    const float* __restrict__ wv,
                                                    float a, float b) {
    __shared__ int   si[KNN];
    __shared__ float sw[KNN];
    __shared__ float part[128][8];
    int n = blockIdx.x;
    int t = threadIdx.x;
    int tt = t & 127, h = t >> 7;
    if (t < KNN) {
        si[t] = idx[(size_t)n * KNN + t];
        sw[t] = wv[(size_t)n * KNN + t];
    }
    __syncthreads();
    int c = tt * 8;
    float acc0 = 0, acc1 = 0, acc2 = 0, acc3 = 0, acc4 = 0, acc5 = 0, acc6 = 0, acc7 = 0;
    int j0 = h * 20;
#pragma unroll 4
    for (int j = j0; j < j0 + 20; ++j) {
        bf16x8 v = *(const bf16x8*)(Tcbf + (size_t)si[j] * KP6 + c);
        float wj = sw[j];
        acc0 += wj * bf2f(v[0]); acc1 += wj * bf2f(v[1]);
        acc2 += wj * bf2f(v[2]); acc3 += wj * bf2f(v[3]);
        acc4 += wj * bf2f(v[4]); acc5 += wj * bf2f(v[5]);
        acc6 += wj * bf2f(v[6]); acc7 += wj * bf2f(v[7]);
    }
    if (h == 1) {
        part[tt][0] = acc0; part[tt][1] = acc1; part[tt][2] = acc2; part[tt][3] = acc3;
        part[tt][4] = acc4; part[tt][5] = acc5; part[tt][6] = acc6; part[tt][7] = acc7;
    }
    __syncthreads();
    if (h == 0) {
        acc0 += part[tt][0]; acc1 += part[tt][1]; acc2 += part[tt][2]; acc3 += part[tt][3];
        acc4 += part[tt][4]; acc5 += part[tt][5]; acc6 += part[tt][6]; acc7 += part[tt][7];
        bf16x8 tc = *(const bf16x8*)(Tcbf + (size_t)n * KP6 + c);
        float o0 = a * (bf2f(tc[0]) - acc0), o1 = a * (bf2f(tc[1]) - acc1);
        float o2 = a * (bf2f(tc[2]) - acc2), o3 = a * (bf2f(tc[3]) - acc3);
        float o4 = a * (bf2f(tc[4]) - acc4), o5 = a * (bf2f(tc[5]) - acc5);
        float o6 = a * (bf2f(tc[6]) - acc6), o7 = a * (bf2f(tc[7]) - acc7);
        if (b != 0.f) {
            bf16x8 tp = *(const bf16x8*)(Tpbf + (size_t)n * KP6 + c);
            o0 -= b * bf2f(tp[0]); o1 -= b * bf2f(tp[1]);
            o2 -= b * bf2f(tp[2]); o3 -= b * bf2f(tp[3]);
            o4 -= b * bf2f(tp[4]); o5 -= b * bf2f(tp[5]);
            o6 -= b * bf2f(tp[6]); o7 -= b * bf2f(tp[7]);
        }
        bf16x8 ob;
        ob[0] = (short)f2bf(o0); ob[1] = (short)f2bf(o1);
        ob[2] = (short)f2bf(o2); ob[3] = (short)f2bf(o3);
        ob[4] = (short)f2bf(o4); ob[5] = (short)f2bf(o5);
        ob[6] = (short)f2bf(o6); ob[7] = (short)f2bf(o7);
        *(bf16x8*)(Tnbf + (size_t)n * KP6 + c) = ob;
    }
}

// ---------------- bf16 conversion / transpose ----------------

__global__ __launch_bounds__(256) void cvt_bf16_kernel(const float* __restrict__ in,
                                                       unsigned short* __restrict__ out) {
    int i = blockIdx.x * 256 + threadIdx.x;
    int r = i >> 7, g = i & 127;
    bf16x8 v;
    if (g < 125) {
        float4 a = *(const float4*)(in + (size_t)r * CC + g * 8);
        float4 b = *(const float4*)(in + (size_t)r * CC + g * 8 + 4);
        v[0] = (short)f2bf(a.x); v[1] = (short)f2bf(a.y);
        v[2] = (short)f2bf(a.z); v[3] = (short)f2bf(a.w);
        v[4] = (short)f2bf(b.x); v[5] = (short)f2bf(b.y);
        v[6] = (short)f2bf(b.z); v[7] = (short)f2bf(b.w);
    } else {
#pragma unroll
        for (int q = 0; q < 8; ++q) v[q] = 0;
    }
    *(bf16x8*)(out + (size_t)r * KP6 + g * 8) = v;
}

// W2 [6*CC x CC] fp32 -> W2T6 [1024 rows(n)][KP6 cols(k)] bf16
__global__ __launch_bounds__(256) void w2t_kernel(const float* __restrict__ W2,
                                                  unsigned short* __restrict__ out) {
    __shared__ unsigned short tile[64][65];
    int t = threadIdx.x;
    int k0 = blockIdx.x * 64, n0 = blockIdx.y * 64, s = blockIdx.z;
#pragma unroll
    for (int p = 0; p < 16; ++p) {
        int i = p * 256 + t;
        int kk = i >> 6, nn = i & 63;
        int k = k0 + kk, n = n0 + nn;
        float v = (k < CC && n < CC) ? W2[((size_t)s * CC + k) * CC + n] : 0.f;
        tile[kk][nn] = f2bf(v);
    }
    __syncthreads();
#pragma unroll
    for (int p = 0; p < 16; ++p) {
        int i = p * 256 + t;
        int nn = i >> 6, kk = i & 63;
        out[(size_t)(n0 + nn) * KP6 + (size_t)s * KP + k0 + kk] = tile[kk][nn];
    }
}

// ---------------- MFMA GEMM cores ----------------

#define LDP 40
#define SP2 136                     // 128-tile epilogue staging pitch
#define SMEMN ((128 + 256) * LDP)   // 256-tile LDS
#define SP 264                      // 256-tile epilogue staging pitch

// 128x128-tile core
template<int STR>
__device__ __forceinline__ void gemm_core128(const unsigned short* __restrict__ Ag,
                                             const unsigned short* __restrict__ Bg,
                                             short* As, short* Bs, int t,
                                             int kbeg, int kend,
                                             f32x4 (&acc)[4][4]) {
    int l = t & 63, w = t >> 6;
    int wm = (w >> 1) * 64, wn = (w & 1) * 64;
    int ar0 = t >> 2, ak0 = (t & 3) * 8;
    int ar1 = (t + 256) >> 2, ak1 = ((t + 256) & 3) * 8;
    int lr = l & 15, lq8 = (l >> 4) * 8;
    for (int k0 = kbeg; k0 < kend; k0 += 32) {
        bf16x8 a0 = *(const bf16x8*)(Ag + (size_t)ar0 * STR + k0 + ak0);
        bf16x8 a1 = *(const bf16x8*)(Ag + (size_t)ar1 * STR + k0 + ak1);
        bf16x8 b0 = *(const bf16x8*)(Bg + (size_t)ar0 * STR + k0 + ak0);
        bf16x8 b1 = *(const bf16x8*)(Bg + (size_t)ar1 * STR + k0 + ak1);
        __syncthreads();
        *(bf16x8*)&As[ar0 * LDP + ak0] = a0;
        *(bf16x8*)&As[ar1 * LDP + ak1] = a1;
        *(bf16x8*)&Bs[ar0 * LDP + ak0] = b0;
        *(bf16x8*)&Bs[ar1 * LDP + ak1] = b1;
        __syncthreads();
        bf16x8 af[4], bfr[4];
#pragma unroll
        for (int mi = 0; mi < 4; ++mi)
            af[mi] = *(const bf16x8*)&As[(wm + mi * 16 + lr) * LDP + lq8];
#pragma unroll
        for (int ni = 0; ni < 4; ++ni)
            bfr[ni] = *(const bf16x8*)&Bs[(wn + ni * 16 + lr) * LDP + lq8];
#pragma unroll
        for (int mi = 0; mi < 4; ++mi)
#pragma unroll
            for (int ni = 0; ni < 4; ++ni)
                acc[mi][ni] = __builtin_amdgcn_mfma_f32_16x16x32_bf16(af[mi], bfr[ni], acc[mi][ni], 0, 0, 0);
    }
}

// 128x256-tile core
template<int STR>
__device__ __forceinline__ void gemm_core256(const unsigned short* __restrict__ Ag,
                                             const unsigned short* __restrict__ Bg,
                                             short* As, short* Bs, int t,
                                             int kbeg, int kend,
                                             f32x4 (&acc)[4][8]) {
    int l = t & 63, w = t >> 6;
    int wm = (w >> 1) * 64, wn = (w & 1) * 128;
    int ar = t >> 1, ak = (t & 1) * 16;
    int lr = l & 15, lq8 = (l >> 4) * 8;
    for (int k0 = kbeg; k0 < kend; k0 += 32) {
        bf16x8 a0 = *(const bf16x8*)(Ag + (size_t)ar * STR + k0 + ak);
        bf16x8 a1 = *(const bf16x8*)(Ag + (size_t)ar * STR + k0 + ak + 8);
        bf16x8 b0 = *(const bf16x8*)(Bg + (size_t)ar * STR + k0 + ak);
        bf16x8 b1 = *(const bf16x8*)(Bg + (size_t)ar * STR + k0 + ak + 8);
        bf16x8 b2 = *(const bf16x8*)(Bg + (size_t)(128 + ar) * STR + k0 + ak);
        bf16x8 b3 = *(const bf16x8*)(Bg + (size_t)(128 + ar) * STR + k0 + ak + 8);
        __syncthreads();
        *(bf16x8*)&As[ar * LDP + ak] = a0;
        *(bf16x8*)&As[ar * LDP + ak + 8] = a1;
        *(bf16x8*)&Bs[ar * LDP + ak] = b0;
        *(bf16x8*)&Bs[ar * LDP + ak + 8] = b1;
        *(bf16x8*)&Bs[(128 + ar) * LDP + ak] = b2;
        *(bf16x8*)&Bs[(128 + ar) * LDP + ak + 8] = b3;
        __syncthreads();
        bf16x8 af[4], bfr[8];
#pragma unroll
        for (int mi = 0; mi < 4; ++mi)
            af[mi] = *(const bf16x8*)&As[(wm + mi * 16 + lr) * LDP + lq8];
#pragma unroll
        for (int ni = 0; ni < 8; ++ni)
            bfr[ni] = *(const bf16x8*)&Bs[(wn + ni * 16 + lr) * LDP + lq8];
#pragma unroll
        for (int mi = 0; mi < 4; ++mi)
#pragma unroll
            for (int ni = 0; ni < 8; ++ni)
                acc[mi][ni] = __builtin_amdgcn_mfma_f32_16x16x32_bf16(af[mi], bfr[ni], acc[mi][ni], 0, 0, 0);
    }
}

// batched cheb2 GEMM: bf16 partials, 128x128 tiles, LDS-staged coalesced stores
// grid (32 m, 8 n, 6 z): same-A blocks 32 apart -> same XCD -> A L2 reuse
__global__ __launch_bounds__(256) void gemm_mfma_big(const unsigned short* __restrict__ A,
                                                     const unsigned short* __restrict__ B,
                                                     unsigned short* __restrict__ Cp) {
    __shared__ short smem[2 * 128 * LDP];
    short* As = smem;
    short* Bs = smem + 128 * LDP;
    int t = threadIdx.x;
    int m0 = blockIdx.x * 128, n0 = blockIdx.y * 128;
    int kz = blockIdx.z;
    unsigned short* C = Cp + (size_t)kz * N4 * CC;
    f32x4 acc[4][4] = {};
    gemm_core128<KP6>(A + (size_t)m0 * KP6, B + (size_t)n0 * KP6, As, Bs, t,
                      kz * KP, kz * KP + KP, acc);
    int l = t & 63, w = t >> 6;
    int wn = (w & 1) * 64;
    int lr = l & 15, lq4 = (l >> 4) * 4;
    int lrow = (w >> 1) * 16 + lq4;
#pragma unroll
    for (int mi = 0; mi < 4; ++mi) {
        __syncthreads();
#pragma unroll
        for (int ni = 0; ni < 4; ++ni) {
            int col = wn + ni * 16 + lr;
            f32x4 v = acc[mi][ni];
#pragma unroll
            for (int r = 0; r < 4; ++r) smem[(lrow + r) * SP2 + col] = (short)f2bf(v[r]);
        }
        __syncthreads();
#pragma unroll
        for (int q = 0; q < 2; ++q) {
            int row = q * 16 + (t >> 4);
            int col = (t & 15) * 8;
            int gm = m0 + (row >> 4) * 64 + mi * 16 + (row & 15);
            int gn = n0 + col;
            if (gn < CC) {
                bf16x8 vv = *(bf16x8*)&smem[row * SP2 + col];
                *(bf16x8*)(C + (size_t)gm * CC + gn) = vv;
            }
        }
    }
}

// out2 = relu(sum_z bf16 Cz + b2) -> fp32 out
__global__ __launch_bounds__(256) void bias_relu_merge(const unsigned short* __restrict__ Cp,
                                                       const float* __restrict__ b2,
                                                       float* __restrict__ out2) {
    size_t i8 = (size_t)blockIdx.x * 256 + threadIdx.x;
    if (i8 >= (size_t)N4 * CC / 8) return;
    size_t i = i8 * 8;
    int c = (int)(i % CC);
    const size_t S = (size_t)N4 * CC;
    float s[8] = {};
#pragma unroll
    for (int z = 0; z < 6; ++z) {
        bf16x8 v = *(const bf16x8*)(Cp + z * S + i);
#pragma unroll
        for (int q = 0; q < 8; ++q) s[q] += bf2f(v[q]);
    }
    float4 o0, o1;
    o0.x = fmaxf(s[0] + b2[c + 0], 0.f); o0.y = fmaxf(s[1] + b2[c + 1], 0.f);
    o0.z = fmaxf(s[2] + b2[c + 2], 0.f); o0.w = fmaxf(s[3] + b2[c + 3], 0.f);
    o1.x = fmaxf(s[4] + b2[c + 4], 0.f); o1.y = fmaxf(s[5] + b2[c + 5], 0.f);
    o1.z = fmaxf(s[6] + b2[c + 6], 0.f); o1.w = fmaxf(s[7] + b2[c + 7], 0.f);
    *(float4*)(out2 + i) = o0;
    *(float4*)(out2 + i + 4) = o1;
}

// gram over Tall slice 0 -> bf16 distances, 128x256 tiles, m-major XCD swizzle
__global__ __launch_bounds__(256, 2) void gram2_mfma(const unsigned short* __restrict__ Tall,
                                                     const float* __restrict__ sq2,
                                                     unsigned short* __restrict__ S) {
    __shared__ short smem[SMEMN];
    short* As = smem;
    short* Bs = smem + 128 * LDP;
    int t = threadIdx.x;
    int m0 = blockIdx.x * 128, n0 = blockIdx.y * 256;
    f32x4 acc[4][8] = {};
    gemm_core256<KP6>(Tall + (size_t)m0 * KP6, Tall + (size_t)n0 * KP6, As, Bs, t, 0, KP, acc);
    int l = t & 63, w = t >> 6;
    int wn = (w & 1) * 128;
    int lr = l & 15, lq4 = (l >> 4) * 4;
    int lrow = (w >> 1) * 16 + lq4;
#pragma unroll
    for (int mi = 0; mi < 4; ++mi) {
        __syncthreads();
        int mbase = m0 + (w >> 1) * 64 + mi * 16 + lq4;
#pragma unroll
        for (int ni = 0; ni < 8; ++ni) {
            int col = wn + ni * 16 + lr;
            float sn = sq2[n0 + col];
            f32x4 v = acc[mi][ni];
#pragma unroll
            for (int r = 0; r < 4; ++r)
                smem[(lrow + r) * SP + col] = (short)f2bf(sq2[mbase + r] + sn - 2.f * v[r]);
        }
        __syncthreads();
#pragma unroll
        for (int q = 0; q < 4; ++q) {
            int row = q * 8 + (t >> 5);
            int col = (t & 31) * 8;
            int gm = m0 + (row >> 4) * 64 + mi * 16 + (row & 15);
            int gn = n0 + col;
            bf16x8 vv = *(bf16x8*)&smem[row * SP + col];
            *(bf16x8*)(S + (size_t)gm * N4 + gn) = vv;
        }
    }
}

// ---------------- cheb conv 1 ----------------

__global__ __launch_bounds__(256) void cheb1_out_kernel(const float* __restrict__ xhat,
                                                        const float* __restrict__ W1,
                                                        const float* __restrict__ b1,
                                                        float* __restrict__ outF) {
    __shared__ float xh[16][18];
    int n0 = blockIdx.x * 16;
    int tid = threadIdx.x;
    for (int i = tid; i < 16 * 18; i += 256) xh[i / 18][i % 18] = xhat[(size_t)n0 * 18 + i];
    __syncthreads();
    for (int c0 = 0; c0 < CC; c0 += 256) {
        int c = c0 + tid;
        if (c < CC) {
            float acc[16];
#pragma unroll
            for (int r = 0; r < 16; ++r) acc[r] = 0.f;
            for (int f = 0; f < 18; ++f) {
                float wv = W1[(size_t)f * CC + c];
#pragma unroll
                for (int r = 0; r < 16; ++r) acc[r] += xh[r][f] * wv;
            }
            float bb = b1[c];
#pragma unroll
            for (int r = 0; r < 16; ++r)
                outF[(size_t)(n0 + r) * CC + c] = fmaxf(acc[r] + bb, 0.f);
        }
    }
}

// ---------------- regs (frobenius of O^T @ T) ----------------

__global__ __launch_bounds__(256) void matT6_partial(const float* __restrict__ O,
                                                     const float* __restrict__ T, int ts,
                                                     float* __restrict__ M) {
    __shared__ float sT[128][6];
    int t = threadIdx.x;
    int c = blockIdx.x * 256 + t;
    int n0 = blockIdx.y * 128;
    for (int i = t; i < 128 * 6; i += 256) {
        int nn = i / 6, f = i % 6;
        sT[nn][f] = T[(size_t)(n0 + nn) * ts + f];
    }
    __syncthreads();
    if (c >= CC) return;
    float a0 = 0, a1 = 0, a2 = 0, a3 = 0, a4 = 0, a5 = 0;
    for (int nn = 0; nn < 128; ++nn) {
        float o = O[(size_t)(n0 + nn) * CC + c];
        a0 += o * sT[nn][0]; a1 += o * sT[nn][1]; a2 += o * sT[nn][2];
        a3 += o * sT[nn][3]; a4 += o * sT[nn][4]; a5 += o * sT[nn][5];
    }
    atomicAdd(&M[0 * CC + c], a0);
    atomicAdd(&M[1 * CC + c], a1);
    atomicAdd(&M[2 * CC + c], a2);
    atomicAdd(&M[3 * CC + c], a3);
    atomicAdd(&M[4 * CC + c], a4);
    atomicAdd(&M[5 * CC + c], a5);
}

__global__ __launch_bounds__(256) void fro_kernel(const float* __restrict__ M, float* __restrict__ dst) {
    __shared__ float red[256];
    int t = threadIdx.x;
    int i = blockIdx.x * 256 + t;
    float v = (i < 6 * CC) ? M[i] : 0.f;
    red[t] = v * v;
    __syncthreads();
    for (int o = 128; o; o >>= 1) { if (t < o) red[t] += red[t + o]; __syncthreads(); }
    if (t == 0) atomicAdd(dst, red[0]);
}

// ---------------- pooling ----------------

__global__ __launch_bounds__(256) void vfr_kernel(const float* __restrict__ outF,
                                                  const int* __restrict__ sccs,
                                                  float* __restrict__ vfr) {
    int r = blockIdx.y;
    int c = blockIdx.x * 256 + threadIdx.x;
    if (c >= CC) return;
    int s0 = blockIdx.z * 41;
    float m = 0.f;
    for (int s = s0; s < s0 + 41; ++s) {
        int n = sccs[r * SSC + s];
        m = fmaxf(m, outF[(size_t)n * CC + c]);
    }
    atomicMax((int*)&vfr[(size_t)r * CC + c], __float_as_int(m));
}

__global__ __launch_bounds__(256) void sq2_kernel(const float* __restrict__ outF,
                                                  float* __restrict__ sq2) {
    int lane = threadIdx.x & 63, w = threadIdx.x >> 6;
    int n = blockIdx.x * 4 + w;
    const float* row = outF + (size_t)n * CC;
    float s = 0.f;
    for (int i = lane; i < CC; i += 64) { float v = row[i]; s += v * v; }
#pragma unroll
    for (int o = 32; o; o >>= 1) s += __shfl_down(s, o);
    if (lane == 0) sq2[n] = s;
}

// row-split column max; dst must be zeroed (values >= 0)
__global__ __launch_bounds__(256) void colmax_kernel(const float* __restrict__ O,
                                                     float* __restrict__ dst) {
    int c = blockIdx.x * 256 + threadIdx.x;
    if (c >= CC) return;
    int n0 = blockIdx.y * 64;
    float m = 0.f;
    for (int n = n0; n < n0 + 64; ++n) m = fmaxf(m, O[(size_t)n * CC + c]);
    atomicMax((int*)&dst[c], __float_as_int(m));
}

// ---------------- reeb branch ----------------

__global__ __launch_bounds__(256) void reeb_mm_kernel(const float* __restrict__ Lr,
                                                      const float* __restrict__ Vin,
                                                      const float* __restrict__ Vsub,
                                                      float* __restrict__ Vout, float a2) {
    int c = blockIdx.x * 256 + threadIdx.x;
    if (c >= CC) return;
    int r = blockIdx.y;
    float s = 0.f;
#pragma unroll
    for (int j = 0; j < NRB; ++j) s += Lr[r * NRB + j] * Vin[(size_t)j * CC + c];
    float v = a2 * s;
    if (Vsub) v -= Vsub[(size_t)r * CC + c];
    Vout[(size_t)r * CC + c] = v;
}

#define RKC 25
__global__ __launch_bounds__(256) void reeb_conv_splitk(const float* __restrict__ vfr,
                                                        const float* __restrict__ tr1,
                                                        const float* __restrict__ tr2,
                                                        const float* __restrict__ Wr,
                                                        float* __restrict__ rpre) {
    __shared__ float sA[NRB][RKC];
    int t = threadIdx.x;
    int kbase = blockIdx.y * RKC;
    for (int i = t; i < NRB * RKC; i += 256) {
        int r = i / RKC, kk = i % RKC;
        int kg = kbase + kk;
        float v;
        if (kg < CC)           v = vfr[(size_t)r * CC + kg];
        else if (kg < 2 * CC)  v = tr1[(size_t)r * CC + kg - CC];
        else                   v = tr2[(size_t)r * CC + kg - 2 * CC];
        sA[r][kk] = v;
    }
    __syncthreads();
    int c = blockIdx.x * 256 + t;
    if (c >= CC) return;
    float acc[NRB];
#pragma unroll
    for (int r = 0; r < NRB; ++r) acc[r] = 0.f;
    for (int kk = 0; kk < RKC; ++kk) {
        float wv = Wr[(size_t)(kbase + kk) * CC + c];
#pragma unroll
        for (int r = 0; r < NRB; ++r) acc[r] += sA[r][kk] * wv;
    }
#pragma unroll
    for (int r = 0; r < NRB; ++r) atomicAdd(&rpre[(size_t)r * CC + c], acc[r]);
}

__global__ __launch_bounds__(256) void reeb_max_kernel(const float* __restrict__ pre,
                                                       const float* __restrict__ br,
                                                       float* __restrict__ rbm) {
    int c = blockIdx.x * 256 + threadIdx.x;
    if (c >= CC) return;
    float bb = br[c];
    float m = 0.f;
    for (int r = 0; r < NRB; ++r) m = fmaxf(m, fmaxf(pre[(size_t)r * CC + c] + bb, 0.f));
    rbm[c] = m;
}

// ---------------- FC head ----------------

__global__ __launch_bounds__(256) void fc1_kernel(const float* __restrict__ rbm,
                                                  const float* __restrict__ otm,
                                                  const float* __restrict__ w,
                                                  float* __restrict__ h1pre) {
    int j = blockIdx.x * 256 + threadIdx.x;
    if (j >= 512) return;
    int i0 = blockIdx.y * 250;
    float s = 0.f;
    for (int i = i0; i < i0 + 250; ++i) {
        float v = (i < CC) ? rbm[i] : otm[i - CC];
        s += v * w[(size_t)i * 512 + j];
    }
    atomicAdd(&h1pre[j], s);
}

__global__ __launch_bounds__(512) void fc23_kernel(const float* __restrict__ h1pre,
                                                   const float* __restrict__ b1f,
                                                   const float* __restrict__ w2,
                                                   const float* __restrict__ b2f,
                                                   const float* __restrict__ w3,
                                                   const float* __restrict__ b3f,
                                                   float* __restrict__ dout) {
    __shared__ float h1[512];
    __shared__ float h2[128];
    int t = threadIdx.x;
    h1[t] = fmaxf(h1pre[t] + b1f[t], 0.f);
    __syncthreads();
    if (t < 128) {
        float s = b2f[t];
        for (int i = 0; i < 512; ++i) s += h1[i] * w2[(size_t)i * 128 + t];
        h2[t] = fmaxf(s, 0.f);
    }
    __syncthreads();
    if (t < 40) {
        float s = b3f[t];
        for (int i = 0; i < 128; ++i) s += h2[i] * w3[(size_t)i * 40 + t];
        dout[t] = s;
    }
}

__global__ __launch_bounds__(256) void finalize_kernel(const float* __restrict__ racc,
                                                       const float* __restrict__ f1w,
                                                       const float* __restrict__ f1b,
                                                       const float* __restrict__ f2w,
                                                       const float* __restrict__ f2b,
                                                       const float* __restrict__ f3w,
                                                       const float* __restrict__ f3b,
                                                       float* __restrict__ dout) {
    __shared__ float red[256];
    __shared__ float res[3];
    int t = threadIdx.x;
    float s1 = 0.f, s2 = 0.f, s3 = 0.f;
    for (int i = t; i < 2000; i += 256) { float v = f1w[(size_t)i * 512]; s1 += v * v; }
    for (int i = t; i < 512; i += 256) { float v = f2w[(size_t)i * 128]; s2 += v * v; }
    if (t < 128) { float v = f3w[(size_t)t * 40]; s3 = v * v; }

    red[t] = s1; __syncthreads();
    for (int o = 128; o; o >>= 1) { if (t < o) red[t] += red[t + o]; __syncthreads(); }
    if (t == 0) res[0] = red[0];
    __syncthreads();
    red[t] = s2; __syncthreads();
    for (int o = 128; o; o >>= 1) { if (t < o) red[t] += red[t + o]; __syncthreads(); }
    if (t == 0) res[1] = red[0];
    __syncthreads();
    red[t] = s3; __syncthreads();
    for (int o = 128; o; o >>= 1) { if (t < o) red[t] += red[t + o]; __syncthreads(); }
    if (t == 0) res[2] = red[0];
    __syncthreads();

    if (t == 0) {
        dout[40] = sqrtf(racc[0]);
        dout[41] = sqrtf(racc[1]);
        dout[42] = res[0];
        dout[43] = f1b[0] * f1b[0];
        dout[44] = res[1];
        dout[45] = f2b[0] * f2b[0];
        dout[46] = res[2];
        dout[47] = f3b[0] * f3b[0];
    }
}

// ---------------- host ----------------

extern "C" void kernel_launch(void* const* d_in, const int* in_sizes, int n_in,
                              void* d_out, int out_size, void* d_ws, size_t ws_size,
                              hipStream_t stream) {
    const float* x    = (const float*)d_in[0];
    const float* Lr   = (const float*)d_in[5];
    const int*   sccs = (const int*)d_in[6];
    const float* W1   = (const float*)d_in[7];
    const float* b1   = (const float*)d_in[8];
    const float* W2   = (const float*)d_in[9];
    const float* b2   = (const float*)d_in[10];
    const float* Wr   = (const float*)d_in[11];
    const float* br   = (const float*)d_in[12];
    const float* f1w  = (const float*)d_in[13];
    const float* f1b  = (const float*)d_in[14];
    const float* f2w  = (const float*)d_in[15];
    const float* f2b  = (const float*)d_in[16];
    const float* f3w  = (const float*)d_in[17];
    const float* f3b  = (const float*)d_in[18];
    float* dout = (float*)d_out;

    char* ws = (char*)d_ws;
    size_t off = 0;
    auto alloc = [&](size_t bytes) -> char* {
        char* p = ws + off;
        off = (off + bytes + 255) & ~(size_t)255;
        return p;
    };
    float* outF = (float*)alloc((size_t)N4 * CC * 4);             // graph1 out, then reused as out2
    unsigned short* Cpb = (unsigned short*)alloc((size_t)6 * N4 * CC * 2);  // bf16 split-K partials
    unsigned short* Sb  = (unsigned short*)alloc((size_t)N4 * N4 * 2);      // bf16 distances
    unsigned short* Tall = (unsigned short*)alloc((size_t)N4 * KP6 * 2);
    unsigned short* W2T6 = Sb;   // alias: Sb dead after topk2
    float* xhat = (float*)alloc((size_t)N4 * 18 * 4);
    float* sq1  = (float*)alloc(N4 * 4);
    float* sq2  = (float*)alloc(N4 * 4);
    float* rs1  = (float*)alloc(N4 * 4);
    float* rs2  = (float*)alloc(N4 * 4);
    float* wv1  = (float*)alloc((size_t)N4 * KNN * 4);
    float* wv2  = (float*)alloc((size_t)N4 * KNN * 4);
    int*   ix1  = (int*)alloc((size_t)N4 * KNN * 4);
    int*   ix2  = (int*)alloc((size_t)N4 * KNN * 4);
    float* t2x  = (float*)alloc((size_t)N4 * FDIM * 4);
    float* tr1  = (float*)alloc((size_t)NRB * CC * 4);
    float* tr2  = (float*)alloc((size_t)NRB * CC * 4);
    char*  zbase = ws + off;
    float* Mb   = (float*)alloc(6 * CC * 4);
    float* Mb2  = (float*)alloc(6 * CC * 4);
    float* rbm  = (float*)alloc(CC * 4);
    float* otm  = (float*)alloc(CC * 4);
    float* h1p  = (float*)alloc(512 * 4);
    float* racc = (float*)alloc(64 * 4);
    float* rpre = (float*)alloc((size_t)NRB * CC * 4);
    float* vfr  = (float*)alloc((size_t)NRB * CC * 4);
    size_t zlen = (size_t)((ws + off) - zbase);
    if (off > ws_size) return;

    hipMemsetAsync(zbase, 0, zlen, stream);

    // ---- graph 1 (on x): fused distance + top-40 ----
    sqx_kernel<<<(N4 + 255) / 256, 256, 0, stream>>>(x, sq1, xhat);
    topk_fused1<<<N4, 512, 0, stream>>>(x, sq1, ix1, wv1, rs1);
    wnorm_kernel<<<(N4 * KNN + 255) / 256, 256, 0, stream>>>(wv1, ix1, rs1);

    // ---- cheb conv 1 ----
    spmv_cheb<<<N4, 64, 0, stream>>>(xhat, xhat, xhat + 6, ix1, wv1, FDIM, 18, 18, 18, 1.f, 0.f);
    spmv_cheb<<<N4, 64, 0, stream>>>(xhat + 6, xhat, xhat + 12, ix1, wv1, FDIM, 18, 18, 18, 2.f, 1.f);
    cheb1_out_kernel<<<N4 / 16, 256, 0, stream>>>(xhat, W1, b1, outF);

    matT6_partial<<<dim3(4, 32), 256, 0, stream>>>(outF, xhat + 6, 18, Mb);
    fro_kernel<<<24, 256, 0, stream>>>(Mb, racc + 0);

    vfr_kernel<<<dim3(4, NRB, 5), 256, 0, stream>>>(outF, sccs, vfr);

    // ---- graph 2 (on outF) ----
    sq2_kernel<<<N4 / 4, 256, 0, stream>>>(outF, sq2);
    cvt_bf16_kernel<<<N4 * 128 / 256, 256, 0, stream>>>(outF, Tall);  // slice 0
    gram2_mfma<<<dim3(N4 / 128, N4 / 256), 256, 0, stream>>>(Tall, sq2, Sb);
    topk_radix<<<N4, 512, 0, stream>>>(Sb, ix2, wv2, rs2);
    wnorm_kernel<<<(N4 * KNN + 255) / 256, 256, 0, stream>>>(wv2, ix2, rs2);

    // Sb dead -> build W2T6 in its space
    w2t_kernel<<<dim3(16, 16, 6), 256, 0, stream>>>(W2, W2T6);

    spmv_cheb<<<N4, 64, 0, stream>>>(x, x, t2x, ix2, wv2, FDIM, FDIM, FDIM, FDIM, 1.f, 0.f);

    // ---- cheb recursion (bf16, into Tall slices 1..5) ----
    spmv_cheb_bf<<<N4, 256, 0, stream>>>(Tall + 0 * KP, Tall + 0 * KP, Tall + 1 * KP, ix2, wv2, 1.f, 0.f);
    spmv_cheb_bf<<<N4, 256, 0, stream>>>(Tall + 1 * KP, Tall + 0 * KP, Tall + 2 * KP, ix2, wv2, 2.f, 1.f);
    spmv_cheb_bf<<<N4, 256, 0, stream>>>(Tall + 2 * KP, Tall + 1 * KP, Tall + 3 * KP, ix2, wv2, 2.f, 1.f);
    spmv_cheb_bf<<<N4, 256, 0, stream>>>(Tall + 3 * KP, Tall + 2 * KP, Tall + 4 * KP, ix2, wv2, 2.f, 1.f);
    spmv_cheb_bf<<<N4, 256, 0, stream>>>(Tall + 4 * KP, Tall + 3 * KP, Tall + 5 * KP, ix2, wv2, 2.f, 1.f);

    // ---- batched K=6144 GEMM (split-K=6, bf16 partials, 128-tiles, XCD-swizzled) ----
    gemm_mfma_big<<<dim3(N4 / 128, 8, 6), 256, 0, stream>>>(Tall, W2T6, Cpb);
    bias_relu_merge<<<(int)(((size_t)N4 * CC / 8 + 255) / 256), 256, 0, stream>>>(Cpb, b2, outF);

    matT6_partial<<<dim3(4, 32), 256, 0, stream>>>(outF, t2x, FDIM, Mb2);
    fro_kernel<<<24, 256, 0, stream>>>(Mb2, racc + 1);

    colmax_kernel<<<dim3(4, 64), 256, 0, stream>>>(outF, otm);

    // ---- reeb cheb conv (K=3) ----
    reeb_mm_kernel<<<dim3(4, NRB), 256, 0, stream>>>(Lr, vfr, nullptr, tr1, 1.f);
    reeb_mm_kernel<<<dim3(4, NRB), 256, 0, stream>>>(Lr, tr1, vfr, tr2, 2.f);
    reeb_conv_splitk<<<dim3(4, 120), 256, 0, stream>>>(vfr, tr1, tr2, Wr, rpre);
    reeb_max_kernel<<<4, 256, 0, stream>>>(rpre, br, rbm);

    // ---- FC head ----
    fc1_kernel<<<dim3(2, 8), 256, 0, stream>>>(rbm, otm, f1w, h1p);
    fc23_kernel<<<1, 512, 0, stream>>>(h1p, f1b, f2w, f2b, f3w, f3b, dout);
    finalize_kernel<<<1, 256, 0, stream>>>(racc, f1w, f1b, f2w, f2b, f3w, f3b, dout);
}